// Round 3
// baseline (250.073 us; speedup 1.0000x reference)
//
#include <hip/hip_runtime.h>
#include <stdint.h>

#define TT 512
#define BB 1024
#define NN 64

typedef __attribute__((ext_vector_type(8))) short short8;
typedef __attribute__((ext_vector_type(4))) float f32x4;

union W8 { uint32_t w[4]; short8 v; };

__device__ __forceinline__ uint32_t cvt_pk_bf16(float lo, float hi){
    uint32_t r;
    asm("v_cvt_pk_bf16_f32 %0, %1, %2" : "=v"(r) : "v"(lo), "v"(hi));
    return r;
}

// Detect input integer widths (harness may canonicalize int64->int32, bool->int32).
__global__ void __launch_bounds__(64, 1)
detect_kernel(const uint32_t* __restrict__ tgt, const uint8_t* __restrict__ msk,
              int* __restrict__ flags) {
    if (threadIdx.x == 0) {
        uint32_t s = 0;
        for (int i = 0; i < 128; ++i) s |= tgt[2 * i + 1];
        flags[0] = (s == 0) ? 1 : 0;   // 1 => target is int64
        uint32_t mz = 0;
        for (int i = 0; i < 8; ++i) mz |= msk[4*i+1] | msk[4*i+2] | msk[4*i+3];
        flags[1] = (mz == 0) ? 1 : 0;  // 1 => mask is int32
    }
}

// Gold-path score: fully parallel over (t, b). score contribution per cell:
//   mask[t,b]*(emit[t,b,tg] + (t>0)*trans[tg_{t-1},tg_t]) + (t==0)*strans[tg0]
//   + (last valid t)*etrans[tg]
__global__ void __launch_bounds__(256)
score_kernel(const float* __restrict__ emit, const float* __restrict__ trans,
             const float* __restrict__ strans, const float* __restrict__ etrans,
             const void* __restrict__ target, const void* __restrict__ mask,
             const int* __restrict__ flags, float* __restrict__ out)
{
    const int idx = blockIdx.x * 256 + threadIdx.x;   // T*B = 524288 threads
    const int t = idx >> 10, b = idx & (BB - 1);
    const int t64 = flags[0], m32 = flags[1];

    auto getm = [&](int tt) -> int {
        if (m32) return ((const int*)mask)[(size_t)tt * BB + b] != 0;
        else     return ((const uint8_t*)mask)[(size_t)tt * BB + b] != 0;
    };
    auto gett = [&](int tt) -> int {
        if (t64) return (int)((const long long*)target)[(size_t)tt * BB + b];
        else     return ((const int*)target)[(size_t)tt * BB + b];
    };

    const int m  = getm(t);
    const int tg = gett(t);
    float term = 0.f;
    if (m)      term += emit[((size_t)t * BB + b) * NN + tg];
    if (t == 0) term += strans[tg];
    if (t > 0 && m) term += trans[gett(t - 1) * NN + tg];
    const int mn = (t == TT - 1) ? 0 : getm(t + 1);
    if (m && !mn) term += etrans[tg];   // t == len-1 (contiguous prefix)

    #pragma unroll
    for (int off = 1; off < 64; off <<= 1) term += __shfl_xor(term, off);
    __shared__ float sred[4];
    const int wid = threadIdx.x >> 6, lane = threadIdx.x & 63;
    if (lane == 0) sred[wid] = term;
    __syncthreads();
    if (threadIdx.x == 0)
        atomicAdd(out, -(sred[0] + sred[1] + sred[2] + sred[3]) * (1.0f / (float)BB));
}

// Forward scan, MFMA formulation. Wave w owns chains 16w..16w+15.
// State S (linear space, carried per-chain log-scale m) lives in MFMA C/D
// layout: lane (q=lane>>4, c=lane&15), reg (mt,r) <-> S[state=16mt+4q+r][chain=c].
// Step: U = E^T * S via 8x mfma_f32_16x16x32_bf16 (M-tiles mt, K-tiles kt),
// then S = active ? U .* exp(emit_t) : S.
__global__ void __launch_bounds__(64, 1)
crf_scan(const float* __restrict__ emit, const float* __restrict__ trans,
         const float* __restrict__ strans, const float* __restrict__ etrans,
         const void* __restrict__ mask, const int* __restrict__ flags,
         float* __restrict__ out)
{
    const int lane = threadIdx.x & 63;
    const int q = lane >> 4;
    const int c = lane & 15;
    const int b = (blockIdx.x << 4) + c;
    const int m32 = flags[1];

    // ---- per-chain length (contiguous-prefix mask), q-lanes split T ----
    int lp = 0;
    if (m32) {
        const int* mp = (const int*)mask;
        #pragma unroll 8
        for (int i = 0; i < 128; ++i)
            lp += (mp[(size_t)(q * 128 + i) * BB + b] != 0) ? 1 : 0;
    } else {
        const uint8_t* mp = (const uint8_t*)mask;
        #pragma unroll 8
        for (int i = 0; i < 128; ++i)
            lp += (mp[(size_t)(q * 128 + i) * BB + b] != 0) ? 1 : 0;
    }
    lp += __shfl_xor(lp, 16);
    lp += __shfl_xor(lp, 32);
    const int len = lp;
    int maxlen = len;
    #pragma unroll
    for (int off = 1; off < 64; off <<= 1)
        maxlen = max(maxlen, __shfl_xor(maxlen, off));

    // ---- A-operand: E^T tiles, E[j][n] = exp(trans[j][n]), bf16, resident ----
    // A-frag (16x32, tile mt,kt): lane holds row = c (= n-16mt), k = 8q+j.
    short8 Ef[4][2];
    #pragma unroll
    for (int mt = 0; mt < 4; ++mt) {
        #pragma unroll
        for (int kt = 0; kt < 2; ++kt) {
            W8 u;
            #pragma unroll
            for (int jj = 0; jj < 8; jj += 2) {
                float f0 = __expf(trans[(size_t)(32*kt + 8*q + jj    ) * NN + 16*mt + c]);
                float f1 = __expf(trans[(size_t)(32*kt + 8*q + jj + 1) * NN + 16*mt + c]);
                u.w[jj >> 1] = cvt_pk_bf16(f0, f1);
            }
            Ef[mt][kt] = u.v;
        }
    }

    // ---- state init: S = exp(strans + emit[0]) ----
    f32x4 S[4];
    float m = 0.f;
    #pragma unroll
    for (int mt = 0; mt < 4; ++mt) {
        f32x4 e0 = *(const f32x4*)(emit + (size_t)b * NN + 16*mt + 4*q);
        #pragma unroll
        for (int r = 0; r < 4; ++r)
            S[mt][r] = __expf(strans[16*mt + 4*q + r] + e0[r]);
    }

    // exact per-chain power-of-2 renorm (chain c's 64 states live on 4 q-lanes)
    auto renorm = [&]() {
        float mx = S[0][0];
        #pragma unroll
        for (int mt = 0; mt < 4; ++mt)
            #pragma unroll
            for (int r = 0; r < 4; ++r)
                mx = fmaxf(mx, S[mt][r]);
        mx = fmaxf(mx, __shfl_xor(mx, 16));
        mx = fmaxf(mx, __shfl_xor(mx, 32));
        int ex = (int)((__float_as_uint(mx) >> 23) & 0xffu) - 127;
        float sc = __uint_as_float((uint32_t)(127 - ex) << 23);   // exact 2^-ex
        #pragma unroll
        for (int mt = 0; mt < 4; ++mt)
            #pragma unroll
            for (int r = 0; r < 4; ++r)
                S[mt][r] *= sc;
        m += (float)ex * 0.6931471805599453f;
    };
    renorm();

    // D->B relayout: B-frag word w (j=2w,2w+1) of kt pulls pk[2kt+(q>>1)][w&1]
    // from lane (2(q&1) + (w>>1))*16 + c.  (derivation checked on 3 cases)
    const int addrL = ((2*(q & 1) + 0) * 16 + c) * 4;
    const int addrH = ((2*(q & 1) + 1) * 16 + c) * 4;
    const bool qlow = (q < 2);

    f32x4 pfA[4], pfB[4];
    auto load_emit = [&](int t, f32x4* buf) {
        const float* p = emit + ((size_t)t * BB + b) * NN + 4*q;
        #pragma unroll
        for (int mt = 0; mt < 4; ++mt)
            buf[mt] = *(const f32x4*)(p + 16*mt);
    };

    auto step = [&](int t, f32x4* buf, int tload) {
        // pack current state to bf16 pairs (r=0,1) and (r=2,3) per mt
        uint32_t pk[4][2];
        #pragma unroll
        for (int mt = 0; mt < 4; ++mt) {
            pk[mt][0] = cvt_pk_bf16(S[mt][0], S[mt][1]);
            pk[mt][1] = cvt_pk_bf16(S[mt][2], S[mt][3]);
        }
        // cross-lane relayout into B-frags (pull both mt candidates, select by q>>1)
        W8 b0, b1;
        #pragma unroll
        for (int w = 0; w < 4; ++w) {
            const int h = w >> 1, p = w & 1;
            const int ad = h ? addrH : addrL;
            uint32_t x0 = (uint32_t)__builtin_amdgcn_ds_bpermute(ad, (int)pk[0][p]);
            uint32_t x1 = (uint32_t)__builtin_amdgcn_ds_bpermute(ad, (int)pk[1][p]);
            b0.w[w] = qlow ? x0 : x1;
            uint32_t y0 = (uint32_t)__builtin_amdgcn_ds_bpermute(ad, (int)pk[2][p]);
            uint32_t y1 = (uint32_t)__builtin_amdgcn_ds_bpermute(ad, (int)pk[3][p]);
            b1.w[w] = qlow ? y0 : y1;
        }
        // U = E^T * S  (8 MFMAs)
        f32x4 U[4];
        #pragma unroll
        for (int mt = 0; mt < 4; ++mt) {
            f32x4 acc = {0.f, 0.f, 0.f, 0.f};
            acc = __builtin_amdgcn_mfma_f32_16x16x32_bf16(Ef[mt][0], b0.v, acc, 0, 0, 0);
            acc = __builtin_amdgcn_mfma_f32_16x16x32_bf16(Ef[mt][1], b1.v, acc, 0, 0, 0);
            U[mt] = acc;
        }
        // emission multiply + mask freeze
        const bool active = (t < len);
        #pragma unroll
        for (int mt = 0; mt < 4; ++mt)
            #pragma unroll
            for (int r = 0; r < 4; ++r) {
                float nv = U[mt][r] * __expf(buf[mt][r]);
                S[mt][r] = active ? nv : S[mt][r];
            }
        if ((t & 3) == 0) renorm();
        load_emit(tload, buf);   // refill this buffer for t+2 (hides HBM/L2 latency)
    };

    if (maxlen > 1) {
        load_emit(1, pfA);
        load_emit(maxlen > 2 ? 2 : 1, pfB);
        int t = 1;
        while (true) {
            step(t, pfA, (t + 2 < maxlen) ? t + 2 : maxlen - 1);
            if (++t >= maxlen) break;
            step(t, pfB, (t + 2 < maxlen) ? t + 2 : maxlen - 1);
            if (++t >= maxlen) break;
        }
    }

    // ---- finalize: logZ_c = m_c + log(sum_s S[s][c] * exp(etrans[s])) ----
    float v = 0.f;
    #pragma unroll
    for (int mt = 0; mt < 4; ++mt)
        #pragma unroll
        for (int r = 0; r < 4; ++r)
            v += S[mt][r] * __expf(etrans[16*mt + 4*q + r]);
    v += __shfl_xor(v, 16);
    v += __shfl_xor(v, 32);
    float lz = (q == 0) ? (m + logf(v)) : 0.f;
    #pragma unroll
    for (int off = 1; off < 64; off <<= 1) lz += __shfl_xor(lz, off);
    if (lane == 0) atomicAdd(out, lz * (1.0f / (float)BB));
}

extern "C" void kernel_launch(void* const* d_in, const int* in_sizes, int n_in,
                              void* d_out, int out_size, void* d_ws, size_t ws_size,
                              hipStream_t stream) {
    const float* emit   = (const float*)d_in[0];
    const float* trans  = (const float*)d_in[1];
    const float* strans = (const float*)d_in[2];
    const float* etrans = (const float*)d_in[3];
    const void*  target = d_in[4];
    const void*  mask   = d_in[5];
    int* flags = (int*)d_ws;

    hipMemsetAsync(d_out, 0, sizeof(float), stream);
    detect_kernel<<<1, 64, 0, stream>>>((const uint32_t*)target,
                                        (const uint8_t*)mask, flags);
    score_kernel<<<(TT * BB) / 256, 256, 0, stream>>>(emit, trans, strans, etrans,
                                                      target, mask, flags, (float*)d_out);
    crf_scan<<<BB / 16, 64, 0, stream>>>(emit, trans, strans, etrans,
                                         mask, flags, (float*)d_out);
}